// Round 1
// baseline (537.741 us; speedup 1.0000x reference)
//
#include <hip/hip_runtime.h>
#include <hip/hip_bf16.h>

// Problem dims
#define B_    4
#define T_    2048
#define D_    1024
#define DH_   1024
#define DFF_  4096
#define MTOT  (B_ * T_)   // 8192 rows

using f32x4  = __attribute__((ext_vector_type(4))) float;
using bf16x8 = __attribute__((ext_vector_type(8))) short;

__device__ __forceinline__ unsigned short f2bf(float f) {
    unsigned u = __builtin_bit_cast(unsigned, f);
    u += 0x7fffu + ((u >> 16) & 1u);     // round-to-nearest-even
    return (unsigned short)(u >> 16);
}
__device__ __forceinline__ float bf2f(unsigned short h) {
    unsigned u = ((unsigned)h) << 16;
    return __builtin_bit_cast(float, u);
}

// ---------------- weight transpose + fp32->bf16 convert ----------------
// src [K][N] fp32 row-major  ->  dst [N][K] bf16 row-major
__global__ __launch_bounds__(256) void transp_f32_bf16(
    const float* __restrict__ src, short* __restrict__ dst, int K, int N) {
    __shared__ float tile[32][33];
    int tk = blockIdx.y * 32, tn = blockIdx.x * 32;
    int tx = threadIdx.x & 31, ty = threadIdx.x >> 5;   // 32 x 8
#pragma unroll
    for (int i = 0; i < 4; i++) {
        int r = ty + i * 8;
        tile[r][tx] = src[(size_t)(tk + r) * N + tn + tx];
    }
    __syncthreads();
#pragma unroll
    for (int i = 0; i < 4; i++) {
        int r = ty + i * 8;   // n offset
        dst[(size_t)(tn + r) * K + tk + tx] = f2bf(tile[tx][r]);
    }
}

__global__ void copyv(const float* __restrict__ s, float* __restrict__ d, int n) {
    int i = blockIdx.x * blockDim.x + threadIdx.x;
    if (i < n) d[i] = s[i];
}

// ---------------- LayerNorm (fp32 in, bf16 out), one block per row (D=1024) ----------------
__global__ __launch_bounds__(256) void ln_rows(
    const float* __restrict__ x, const float* __restrict__ g,
    const float* __restrict__ bta, short* __restrict__ out) {
    int row = blockIdx.x;
    const float* xr = x + (size_t)row * D_;
    int t = threadIdx.x;
    float4 v = *(const float4*)(xr + t * 4);
    float s  = v.x + v.y + v.z + v.w;
    float s2 = v.x * v.x + v.y * v.y + v.z * v.z + v.w * v.w;
#pragma unroll
    for (int off = 1; off < 64; off <<= 1) {
        s  += __shfl_xor(s, off);
        s2 += __shfl_xor(s2, off);
    }
    __shared__ float as_[4], as2_[4];
    int wave = t >> 6, lane = t & 63;
    if (lane == 0) { as_[wave] = s; as2_[wave] = s2; }
    __syncthreads();
    s  = as_[0] + as_[1] + as_[2] + as_[3];
    s2 = as2_[0] + as2_[1] + as2_[2] + as2_[3];
    float mean = s * (1.0f / D_);
    float var  = s2 * (1.0f / D_) - mean * mean;
    float rstd = rsqrtf(var + 1e-5f);
    float4 gv = *(const float4*)(g + t * 4);
    float4 bv = *(const float4*)(bta + t * 4);
    short4 o;
    o.x = f2bf((v.x - mean) * rstd * gv.x + bv.x);
    o.y = f2bf((v.y - mean) * rstd * gv.y + bv.y);
    o.z = f2bf((v.z - mean) * rstd * gv.z + bv.z);
    o.w = f2bf((v.w - mean) * rstd * gv.w + bv.w);
    *(short4*)(out + (size_t)row * D_ + t * 4) = o;
}

// ---------------- row softmax over T_=2048 fp32, writes bf16 P in place ----------------
// P row r occupies the first 4096 bytes of fp32 row r (bf16 ld = 4096 shorts).
__global__ __launch_bounds__(256) void softmax_rows(float* __restrict__ S) {
    size_t row = blockIdx.x;
    float* sr = S + row * (size_t)T_;
    int t = threadIdx.x;
    float4 v0 = *(const float4*)(sr + t * 4);
    float4 v1 = *(const float4*)(sr + 1024 + t * 4);
    const float c = 0.03125f;   // 1/sqrt(1024)
    float vv[8] = {v0.x * c, v0.y * c, v0.z * c, v0.w * c,
                   v1.x * c, v1.y * c, v1.z * c, v1.w * c};
    float mx = -1e30f;
#pragma unroll
    for (int i = 0; i < 8; i++) mx = fmaxf(mx, vv[i]);
#pragma unroll
    for (int off = 1; off < 64; off <<= 1) mx = fmaxf(mx, __shfl_xor(mx, off));
    __shared__ float sm[4], ss[4];
    int wave = t >> 6, lane = t & 63;
    if (lane == 0) sm[wave] = mx;
    __syncthreads();
    mx = fmaxf(fmaxf(sm[0], sm[1]), fmaxf(sm[2], sm[3]));
    float sum = 0.f;
#pragma unroll
    for (int i = 0; i < 8; i++) { vv[i] = expf(vv[i] - mx); sum += vv[i]; }
#pragma unroll
    for (int off = 1; off < 64; off <<= 1) sum += __shfl_xor(sum, off);
    if (lane == 0) ss[wave] = sum;
    __syncthreads();
    sum = ss[0] + ss[1] + ss[2] + ss[3];
    float inv = 1.0f / sum;
    short* pr = (short*)sr;
    short4 oa, ob;
    oa.x = f2bf(vv[0] * inv); oa.y = f2bf(vv[1] * inv);
    oa.z = f2bf(vv[2] * inv); oa.w = f2bf(vv[3] * inv);
    ob.x = f2bf(vv[4] * inv); ob.y = f2bf(vv[5] * inv);
    ob.z = f2bf(vv[6] * inv); ob.w = f2bf(vv[7] * inv);
    *(short4*)(pr + t * 4) = oa;
    *(short4*)(pr + 1024 + t * 4) = ob;
}

// ---------------- GEMM: C[m][n] = sum_k A[m][k] * Bt[n][k]  (+epilogue) ----------------
// 128x128 tile, 4 waves (2x2), each wave 64x64 = 4x4 frags of 16x16x32 bf16 MFMA.
// BIAS_MODE: 0 none, 1 bias[col], 2 bias[row].  ACT: 0 none, 1 exact GELU.
// RES: add fp32 residual.  OUT_BF16: 1 -> bf16 C, 0 -> fp32 C.
template<int BIAS_MODE, int ACT, int RES, int OUT_BF16>
__global__ __launch_bounds__(256) void gemm_bt(
    const short* __restrict__ A, int lda, long long sA,
    const short* __restrict__ Bt, int ldb, long long sB,
    void* __restrict__ C, int ldc, long long sC,
    const float* __restrict__ bias,
    const float* __restrict__ res, int ldr, long long sR,
    int K) {
    int z = blockIdx.z;
    A  += (size_t)z * sA;
    Bt += (size_t)z * sB;
    int bm = blockIdx.y * 128, bn = blockIdx.x * 128;
    int tid = threadIdx.x, lane = tid & 63, wave = tid >> 6;
    int wm = (wave >> 1) * 64, wn = (wave & 1) * 64;
    // padded to 40 shorts/row: row-to-row bank step 20 -> conflict-free frag reads
    __shared__ short lsA[128 * 40];
    __shared__ short lsB[128 * 40];
    f32x4 acc[4][4] = {};
    for (int k0 = 0; k0 < K; k0 += 32) {
#pragma unroll
        for (int i = 0; i < 2; i++) {
            int v = tid + i * 256;
            int row = v >> 2, cv = (v & 3) * 8;
            *(bf16x8*)&lsA[row * 40 + cv] =
                *(const bf16x8*)(A + (size_t)(bm + row) * lda + k0 + cv);
            *(bf16x8*)&lsB[row * 40 + cv] =
                *(const bf16x8*)(Bt + (size_t)(bn + row) * ldb + k0 + cv);
        }
        __syncthreads();
        bf16x8 af[4], bf[4];
#pragma unroll
        for (int f = 0; f < 4; f++) {
            af[f] = *(const bf16x8*)&lsA[(wm + f * 16 + (lane & 15)) * 40 + (lane >> 4) * 8];
            bf[f] = *(const bf16x8*)&lsB[(wn + f * 16 + (lane & 15)) * 40 + (lane >> 4) * 8];
        }
#pragma unroll
        for (int fr = 0; fr < 4; fr++)
#pragma unroll
            for (int fn = 0; fn < 4; fn++)
                acc[fr][fn] = __builtin_amdgcn_mfma_f32_16x16x32_bf16(
                    af[fr], bf[fn], acc[fr][fn], 0, 0, 0);
        __syncthreads();
    }
    // epilogue: C/D layout col = lane&15, row = (lane>>4)*4 + r  [m89/m91 verified]
    size_t zc = (size_t)z * (size_t)sC;
#pragma unroll
    for (int fr = 0; fr < 4; fr++) {
#pragma unroll
        for (int fn = 0; fn < 4; fn++) {
            int col = bn + wn + fn * 16 + (lane & 15);
#pragma unroll
            for (int r = 0; r < 4; r++) {
                int row = bm + wm + fr * 16 + (lane >> 4) * 4 + r;
                float v = acc[fr][fn][r];
                if (BIAS_MODE == 1) v += bias[col];
                else if (BIAS_MODE == 2) v += bias[row];
                if (ACT == 1) v = 0.5f * v * (1.0f + erff(v * 0.70710678118654752f));
                if (RES) v += res[(size_t)z * sR + (size_t)row * ldr + col];
                if (OUT_BF16) ((short*)C)[zc + (size_t)row * ldc + col] = f2bf(v);
                else          ((float*)C)[zc + (size_t)row * ldc + col] = v;
            }
        }
    }
}

extern "C" void kernel_launch(void* const* d_in, const int* in_sizes, int n_in,
                              void* d_out, int out_size, void* d_ws, size_t ws_size,
                              hipStream_t stream) {
    const float* x    = (const float*)d_in[0];
    const float* ln1g = (const float*)d_in[1];
    const float* ln1b = (const float*)d_in[2];
    const float* Wq   = (const float*)d_in[3];
    const float* bq   = (const float*)d_in[4];
    const float* Wk   = (const float*)d_in[5];
    const float* bk   = (const float*)d_in[6];
    const float* Wv   = (const float*)d_in[7];
    const float* bv   = (const float*)d_in[8];
    const float* ln2g = (const float*)d_in[9];
    const float* ln2b = (const float*)d_in[10];
    const float* Win  = (const float*)d_in[11];
    const float* bin  = (const float*)d_in[12];
    const float* Wout = (const float*)d_in[13];
    const float* bout = (const float*)d_in[14];

    char* ws = (char*)d_ws;
    size_t off = 0;
    auto alloc = [&](size_t bytes) {
        void* p = ws + off;
        off += (bytes + 255) & ~(size_t)255;
        return p;
    };
    short* WqkT  = (short*)alloc((size_t)2048 * 1024 * 2);  // [2048][1024] = [Wq^T ; Wk^T]
    short* WvT   = (short*)alloc((size_t)1024 * 1024 * 2);  // [1024][1024]
    short* WinT  = (short*)alloc((size_t)4096 * 1024 * 2);  // [4096][1024]
    short* WoutT = (short*)alloc((size_t)1024 * 4096 * 2);  // [1024][4096]
    float* bqk   = (float*)alloc((size_t)2048 * 4);
    short* h     = (short*)alloc((size_t)MTOT * 1024 * 2);  // LN output (reused for LN2)
    short* QK    = (short*)alloc((size_t)MTOT * 2048 * 2);  // [8192][2048] = [Q | K]
    short* VT    = (short*)alloc((size_t)1024 * 8192 * 2);  // V^T [1024][8192]
    float* S     = (float*)alloc((size_t)4 * 2048 * 2048 * 4); // scores fp32; P bf16 + ff alias
    float* x1    = (float*)alloc((size_t)MTOT * 1024 * 4);  // x + attn_out (fp32)
    (void)ws_size; (void)in_sizes; (void)n_in; (void)out_size;

    // --- weights -> bf16 [N][K] ---
    transp_f32_bf16<<<dim3(32, 32), 256, 0, stream>>>(Wq, WqkT, 1024, 1024);
    transp_f32_bf16<<<dim3(32, 32), 256, 0, stream>>>(Wk, WqkT + (size_t)1024 * 1024, 1024, 1024);
    transp_f32_bf16<<<dim3(32, 32), 256, 0, stream>>>(Wv, WvT, 1024, 1024);
    transp_f32_bf16<<<dim3(128, 32), 256, 0, stream>>>(Win, WinT, 1024, 4096);
    transp_f32_bf16<<<dim3(32, 128), 256, 0, stream>>>(Wout, WoutT, 4096, 1024);
    copyv<<<4, 256, 0, stream>>>(bq, bqk, 1024);
    copyv<<<4, 256, 0, stream>>>(bk, bqk + 1024, 1024);

    // --- LN1: x -> h (bf16) ---
    ln_rows<<<MTOT, 256, 0, stream>>>(x, ln1g, ln1b, h);

    // --- [Q|K] = h @ [Wq|Wk] + [bq|bk] : M=8192 N=2048 K=1024, bf16 out ---
    gemm_bt<1, 0, 0, 1><<<dim3(16, 64, 1), 256, 0, stream>>>(
        h, 1024, 0, WqkT, 1024, 0, QK, 2048, 0, bqk, nullptr, 0, 0, 1024);

    // --- V^T = Wv^T @ h^T + bv (per-row): M=1024 N=8192 K=1024, bf16 out ---
    gemm_bt<2, 0, 0, 1><<<dim3(64, 8, 1), 256, 0, stream>>>(
        WvT, 1024, 0, h, 1024, 0, VT, 8192, 0, bv, nullptr, 0, 0, 1024);

    // --- scores: per batch  S = Q_b @ K_b^T : M=N=2048 K=1024, fp32 out ---
    gemm_bt<0, 0, 0, 0><<<dim3(16, 16, 4), 256, 0, stream>>>(
        QK, 2048, 4194304LL, QK + 1024, 2048, 4194304LL,
        S, 2048, 4194304LL, nullptr, nullptr, 0, 0, 1024);

    // --- softmax(S/32) -> P bf16 in place (P ld = 4096 shorts) ---
    softmax_rows<<<MTOT, 256, 0, stream>>>(S);

    // --- attn_out + x: per batch  x1 = P_b @ V_b + x : M=2048 N=1024 K=2048 ---
    gemm_bt<0, 0, 1, 0><<<dim3(8, 16, 4), 256, 0, stream>>>(
        (short*)S, 4096, 8388608LL, VT, 8192, 2048LL,
        x1, 1024, 2097152LL, nullptr, x, 1024, 2097152LL, 2048);

    // --- LN2: x1 -> h (bf16, reuse) ---
    ln_rows<<<MTOT, 256, 0, stream>>>(x1, ln2g, ln2b, h);

    // --- FF1: ff = gelu(h @ Win + bin) : M=8192 N=4096 K=1024, bf16 out (aliases S) ---
    short* ff = (short*)S;
    gemm_bt<1, 1, 0, 1><<<dim3(32, 64, 1), 256, 0, stream>>>(
        h, 1024, 0, WinT, 1024, 0, ff, 4096, 0, bin, nullptr, 0, 0, 1024);

    // --- FF2: out = ff @ Wout + bout + x1 : M=8192 N=1024 K=4096, fp32 out ---
    gemm_bt<1, 0, 1, 0><<<dim3(8, 64, 1), 256, 0, stream>>>(
        ff, 4096, 0, WoutT, 4096, 0, (float*)d_out, 1024, 0, bout,
        x1, 1024, 0, 4096);
}

// Round 2
// 506.105 us; speedup vs baseline: 1.0625x; 1.0625x over previous
//
#include <hip/hip_runtime.h>
#include <hip/hip_bf16.h>

// Problem dims
#define B_    4
#define T_    2048
#define D_    1024
#define DH_   1024
#define DFF_  4096
#define MTOT  (B_ * T_)   // 8192 rows

using f32x4  = __attribute__((ext_vector_type(4))) float;
using bf16x8 = __attribute__((ext_vector_type(8))) short;

__device__ __forceinline__ unsigned short f2bf(float f) {
    unsigned u = __builtin_bit_cast(unsigned, f);
    u += 0x7fffu + ((u >> 16) & 1u);     // round-to-nearest-even
    return (unsigned short)(u >> 16);
}

// async global->LDS, 16B per lane; LDS dest is wave-uniform base + lane*16
__device__ __forceinline__ void gload16(const short* g, short* l) {
    __builtin_amdgcn_global_load_lds(
        (const __attribute__((address_space(1))) unsigned int*)g,
        (__attribute__((address_space(3))) unsigned int*)l, 16, 0, 0);
}

// ---------------- weight transpose + fp32->bf16 convert ----------------
// src [K][N] fp32 row-major  ->  dst [N][K] bf16 row-major
__global__ __launch_bounds__(256) void transp_f32_bf16(
    const float* __restrict__ src, short* __restrict__ dst, int K, int N) {
    __shared__ float tile[32][33];
    int tk = blockIdx.y * 32, tn = blockIdx.x * 32;
    int tx = threadIdx.x & 31, ty = threadIdx.x >> 5;   // 32 x 8
#pragma unroll
    for (int i = 0; i < 4; i++) {
        int r = ty + i * 8;
        tile[r][tx] = src[(size_t)(tk + r) * N + tn + tx];
    }
    __syncthreads();
#pragma unroll
    for (int i = 0; i < 4; i++) {
        int r = ty + i * 8;   // n offset
        dst[(size_t)(tn + r) * K + tk + tx] = f2bf(tile[tx][r]);
    }
}

__global__ void copyv(const float* __restrict__ s, float* __restrict__ d, int n) {
    int i = blockIdx.x * blockDim.x + threadIdx.x;
    if (i < n) d[i] = s[i];
}

// ---------------- LayerNorm (fp32 in, bf16 out), one block per row (D=1024) ----------------
__global__ __launch_bounds__(256) void ln_rows(
    const float* __restrict__ x, const float* __restrict__ g,
    const float* __restrict__ bta, short* __restrict__ out) {
    int row = blockIdx.x;
    const float* xr = x + (size_t)row * D_;
    int t = threadIdx.x;
    float4 v = *(const float4*)(xr + t * 4);
    float s  = v.x + v.y + v.z + v.w;
    float s2 = v.x * v.x + v.y * v.y + v.z * v.z + v.w * v.w;
#pragma unroll
    for (int off = 1; off < 64; off <<= 1) {
        s  += __shfl_xor(s, off);
        s2 += __shfl_xor(s2, off);
    }
    __shared__ float as_[4], as2_[4];
    int wave = t >> 6, lane = t & 63;
    if (lane == 0) { as_[wave] = s; as2_[wave] = s2; }
    __syncthreads();
    s  = as_[0] + as_[1] + as_[2] + as_[3];
    s2 = as2_[0] + as2_[1] + as2_[2] + as2_[3];
    float mean = s * (1.0f / D_);
    float var  = s2 * (1.0f / D_) - mean * mean;
    float rstd = rsqrtf(var + 1e-5f);
    float4 gv = *(const float4*)(g + t * 4);
    float4 bv = *(const float4*)(bta + t * 4);
    short4 o;
    o.x = f2bf((v.x - mean) * rstd * gv.x + bv.x);
    o.y = f2bf((v.y - mean) * rstd * gv.y + bv.y);
    o.z = f2bf((v.z - mean) * rstd * gv.z + bv.z);
    o.w = f2bf((v.w - mean) * rstd * gv.w + bv.w);
    *(short4*)(out + (size_t)row * D_ + t * 4) = o;
}

// ---------------- row softmax over T_=2048 fp32, writes bf16 P in place ----------------
__global__ __launch_bounds__(256) void softmax_rows(float* __restrict__ S) {
    size_t row = blockIdx.x;
    float* sr = S + row * (size_t)T_;
    int t = threadIdx.x;
    float4 v0 = *(const float4*)(sr + t * 4);
    float4 v1 = *(const float4*)(sr + 1024 + t * 4);
    const float c = 0.03125f;   // 1/sqrt(1024)
    float vv[8] = {v0.x * c, v0.y * c, v0.z * c, v0.w * c,
                   v1.x * c, v1.y * c, v1.z * c, v1.w * c};
    float mx = -1e30f;
#pragma unroll
    for (int i = 0; i < 8; i++) mx = fmaxf(mx, vv[i]);
#pragma unroll
    for (int off = 1; off < 64; off <<= 1) mx = fmaxf(mx, __shfl_xor(mx, off));
    __shared__ float sm[4], ss[4];
    int wave = t >> 6, lane = t & 63;
    if (lane == 0) sm[wave] = mx;
    __syncthreads();
    mx = fmaxf(fmaxf(sm[0], sm[1]), fmaxf(sm[2], sm[3]));
    float sum = 0.f;
#pragma unroll
    for (int i = 0; i < 8; i++) { vv[i] = expf(vv[i] - mx); sum += vv[i]; }
#pragma unroll
    for (int off = 1; off < 64; off <<= 1) sum += __shfl_xor(sum, off);
    if (lane == 0) ss[wave] = sum;
    __syncthreads();
    sum = ss[0] + ss[1] + ss[2] + ss[3];
    float inv = 1.0f / sum;
    short* pr = (short*)sr;
    short4 oa, ob;
    oa.x = f2bf(vv[0] * inv); oa.y = f2bf(vv[1] * inv);
    oa.z = f2bf(vv[2] * inv); oa.w = f2bf(vv[3] * inv);
    ob.x = f2bf(vv[4] * inv); ob.y = f2bf(vv[5] * inv);
    ob.z = f2bf(vv[6] * inv); ob.w = f2bf(vv[7] * inv);
    *(short4*)(pr + t * 4) = oa;
    *(short4*)(pr + 1024 + t * 4) = ob;
}

// ---------------- GEMM: C[m][n] = sum_k A[m][k] * Bt[n][k]  (+epilogue) ----------------
// m97 structure: 128x128 tile, BK=32, linear LDS [128][32] bf16,
// global_load_lds width=16 staging, 4 waves (2x2), 4x4 frags 16x16x32 bf16.
// BIAS_MODE: 0 none, 1 bias[col], 2 bias[row].  ACT: 0 none, 1 exact GELU.
// RES: add fp32 residual.  OUT_BF16: 1 -> bf16 C, 0 -> fp32 C.
template<int BIAS_MODE, int ACT, int RES, int OUT_BF16>
__global__ __launch_bounds__(256) void gemm_bt(
    const short* __restrict__ A, int lda, long long sA,
    const short* __restrict__ Bt, int ldb, long long sB,
    void* __restrict__ C, int ldc, long long sC,
    const float* __restrict__ bias,
    const float* __restrict__ res, int ldr, long long sR,
    int K) {
    int z = blockIdx.z;
    A  += (size_t)z * sA;
    Bt += (size_t)z * sB;
    int bm = blockIdx.y * 128, bn = blockIdx.x * 128;
    int tid = threadIdx.x, lane = tid & 63, wave = tid >> 6;
    int wm = (wave >> 1) * 64, wn = (wave & 1) * 64;

    __shared__ short lsA[128 * 32];   // linear, row stride 32 shorts
    __shared__ short lsB[128 * 32];

    // staging geometry: chunk c = wave*2 + i (c in 0..7) covers rows c*16..c*16+15,
    // lane writes LDS byte (c*1024 + lane*16)  ==  row (c*16 + lane/4), kcol (lane%4)*8
    int srow = wave * 32 + (lane >> 2);         // chunk0 row for this lane
    int kb   = (lane & 3) * 8;                  // k element offset within BK=32
    const short* pA0 = A  + (size_t)(bm + srow) * lda + kb;
    const short* pA1 = pA0 + (size_t)16 * lda;
    const short* pB0 = Bt + (size_t)(bn + srow) * ldb + kb;
    const short* pB1 = pB0 + (size_t)16 * ldb;
    short* lA0 = &lsA[(wave * 2 + 0) * 512];
    short* lA1 = &lsA[(wave * 2 + 1) * 512];
    short* lB0 = &lsB[(wave * 2 + 0) * 512];
    short* lB1 = &lsB[(wave * 2 + 1) * 512];

    f32x4 acc[4][4] = {};
    for (int k0 = 0; k0 < K; k0 += 32) {
        gload16(pA0, lA0);
        gload16(pA1, lA1);
        gload16(pB0, lB0);
        gload16(pB1, lB1);
        pA0 += 32; pA1 += 32; pB0 += 32; pB1 += 32;
        __syncthreads();   // compiler emits vmcnt(0) drain before barrier
        bf16x8 af[4], bf[4];
#pragma unroll
        for (int f = 0; f < 4; f++) {
            af[f] = *(const bf16x8*)&lsA[(wm + f * 16 + (lane & 15)) * 32 + (lane >> 4) * 8];
            bf[f] = *(const bf16x8*)&lsB[(wn + f * 16 + (lane & 15)) * 32 + (lane >> 4) * 8];
        }
#pragma unroll
        for (int fr = 0; fr < 4; fr++)
#pragma unroll
            for (int fn = 0; fn < 4; fn++)
                acc[fr][fn] = __builtin_amdgcn_mfma_f32_16x16x32_bf16(
                    af[fr], bf[fn], acc[fr][fn], 0, 0, 0);
        __syncthreads();
    }
    // epilogue: C/D layout col = lane&15, row = (lane>>4)*4 + r  [m89/m91 verified]
    size_t zc = (size_t)z * (size_t)sC;
#pragma unroll
    for (int fr = 0; fr < 4; fr++) {
#pragma unroll
        for (int fn = 0; fn < 4; fn++) {
            int col = bn + wn + fn * 16 + (lane & 15);
#pragma unroll
            for (int r = 0; r < 4; r++) {
                int row = bm + wm + fr * 16 + (lane >> 4) * 4 + r;
                float v = acc[fr][fn][r];
                if (BIAS_MODE == 1) v += bias[col];
                else if (BIAS_MODE == 2) v += bias[row];
                if (ACT == 1) v = 0.5f * v * (1.0f + erff(v * 0.70710678118654752f));
                if (RES) v += res[(size_t)z * sR + (size_t)row * ldr + col];
                if (OUT_BF16) ((short*)C)[zc + (size_t)row * ldc + col] = f2bf(v);
                else          ((float*)C)[zc + (size_t)row * ldc + col] = v;
            }
        }
    }
}

extern "C" void kernel_launch(void* const* d_in, const int* in_sizes, int n_in,
                              void* d_out, int out_size, void* d_ws, size_t ws_size,
                              hipStream_t stream) {
    const float* x    = (const float*)d_in[0];
    const float* ln1g = (const float*)d_in[1];
    const float* ln1b = (const float*)d_in[2];
    const float* Wq   = (const float*)d_in[3];
    const float* bq   = (const float*)d_in[4];
    const float* Wk   = (const float*)d_in[5];
    const float* bk   = (const float*)d_in[6];
    const float* Wv   = (const float*)d_in[7];
    const float* bv   = (const float*)d_in[8];
    const float* ln2g = (const float*)d_in[9];
    const float* ln2b = (const float*)d_in[10];
    const float* Win  = (const float*)d_in[11];
    const float* bin  = (const float*)d_in[12];
    const float* Wout = (const float*)d_in[13];
    const float* bout = (const float*)d_in[14];

    char* ws = (char*)d_ws;
    size_t off = 0;
    auto alloc = [&](size_t bytes) {
        void* p = ws + off;
        off += (bytes + 255) & ~(size_t)255;
        return p;
    };
    short* WqkT  = (short*)alloc((size_t)2048 * 1024 * 2);  // [2048][1024] = [Wq^T ; Wk^T]
    short* WvT   = (short*)alloc((size_t)1024 * 1024 * 2);  // [1024][1024]
    short* WinT  = (short*)alloc((size_t)4096 * 1024 * 2);  // [4096][1024]
    short* WoutT = (short*)alloc((size_t)1024 * 4096 * 2);  // [1024][4096]
    float* bqk   = (float*)alloc((size_t)2048 * 4);
    short* h     = (short*)alloc((size_t)MTOT * 1024 * 2);  // LN output (reused for LN2)
    short* QK    = (short*)alloc((size_t)MTOT * 2048 * 2);  // [8192][2048] = [Q | K]
    short* VT    = (short*)alloc((size_t)1024 * 8192 * 2);  // V^T [1024][8192]
    float* S     = (float*)alloc((size_t)4 * 2048 * 2048 * 4); // scores fp32; P bf16 + ff alias
    float* x1    = (float*)alloc((size_t)MTOT * 1024 * 4);  // x + attn_out (fp32)
    (void)ws_size; (void)in_sizes; (void)n_in; (void)out_size;

    // --- weights -> bf16 [N][K] ---
    transp_f32_bf16<<<dim3(32, 32), 256, 0, stream>>>(Wq, WqkT, 1024, 1024);
    transp_f32_bf16<<<dim3(32, 32), 256, 0, stream>>>(Wk, WqkT + (size_t)1024 * 1024, 1024, 1024);
    transp_f32_bf16<<<dim3(32, 32), 256, 0, stream>>>(Wv, WvT, 1024, 1024);
    transp_f32_bf16<<<dim3(128, 32), 256, 0, stream>>>(Win, WinT, 1024, 4096);
    transp_f32_bf16<<<dim3(32, 128), 256, 0, stream>>>(Wout, WoutT, 4096, 1024);
    copyv<<<4, 256, 0, stream>>>(bq, bqk, 1024);
    copyv<<<4, 256, 0, stream>>>(bk, bqk + 1024, 1024);

    // --- LN1: x -> h (bf16) ---
    ln_rows<<<MTOT, 256, 0, stream>>>(x, ln1g, ln1b, h);

    // --- [Q|K] = h @ [Wq|Wk] + [bq|bk] : M=8192 N=2048 K=1024, bf16 out ---
    gemm_bt<1, 0, 0, 1><<<dim3(16, 64, 1), 256, 0, stream>>>(
        h, 1024, 0, WqkT, 1024, 0, QK, 2048, 0, bqk, nullptr, 0, 0, 1024);

    // --- V^T = Wv^T @ h^T + bv (per-row): M=1024 N=8192 K=1024, bf16 out ---
    gemm_bt<2, 0, 0, 1><<<dim3(64, 8, 1), 256, 0, stream>>>(
        WvT, 1024, 0, h, 1024, 0, VT, 8192, 0, bv, nullptr, 0, 0, 1024);

    // --- scores: per batch  S = Q_b @ K_b^T : M=N=2048 K=1024, fp32 out ---
    gemm_bt<0, 0, 0, 0><<<dim3(16, 16, 4), 256, 0, stream>>>(
        QK, 2048, 4194304LL, QK + 1024, 2048, 4194304LL,
        S, 2048, 4194304LL, nullptr, nullptr, 0, 0, 1024);

    // --- softmax(S/32) -> P bf16 in place (P ld = 4096 shorts) ---
    softmax_rows<<<MTOT, 256, 0, stream>>>(S);

    // --- attn_out + x: per batch  x1 = P_b @ V_b + x : M=2048 N=1024 K=2048 ---
    gemm_bt<0, 0, 1, 0><<<dim3(8, 16, 4), 256, 0, stream>>>(
        (short*)S, 4096, 8388608LL, VT, 8192, 2048LL,
        x1, 1024, 2097152LL, nullptr, x, 1024, 2097152LL, 2048);

    // --- LN2: x1 -> h (bf16, reuse) ---
    ln_rows<<<MTOT, 256, 0, stream>>>(x1, ln2g, ln2b, h);

    // --- FF1: ff = gelu(h @ Win + bin) : M=8192 N=4096 K=1024, bf16 out (aliases S) ---
    short* ff = (short*)S;
    gemm_bt<1, 1, 0, 1><<<dim3(32, 64, 1), 256, 0, stream>>>(
        h, 1024, 0, WinT, 1024, 0, ff, 4096, 0, bin, nullptr, 0, 0, 1024);

    // --- FF2: out = ff @ Wout + bout + x1 : M=8192 N=1024 K=4096, fp32 out ---
    gemm_bt<1, 0, 1, 0><<<dim3(8, 64, 1), 256, 0, stream>>>(
        ff, 4096, 0, WoutT, 4096, 0, (float*)d_out, 1024, 0, bout,
        x1, 1024, 0, 4096);
}

// Round 3
// 464.003 us; speedup vs baseline: 1.1589x; 1.0907x over previous
//
#include <hip/hip_runtime.h>
#include <hip/hip_bf16.h>

// Problem dims
#define B_    4
#define T_    2048
#define D_    1024
#define DH_   1024
#define DFF_  4096
#define MTOT  (B_ * T_)   // 8192 rows

using f32x4  = __attribute__((ext_vector_type(4))) float;
using bf16x8 = __attribute__((ext_vector_type(8))) short;

__device__ __forceinline__ unsigned short f2bf(float f) {
    unsigned u = __builtin_bit_cast(unsigned, f);
    u += 0x7fffu + ((u >> 16) & 1u);     // round-to-nearest-even
    return (unsigned short)(u >> 16);
}

// async global->LDS, 16B per lane; LDS dest is wave-uniform base + lane*16
__device__ __forceinline__ void gload16(const short* g, short* l) {
    __builtin_amdgcn_global_load_lds(
        (const __attribute__((address_space(1))) unsigned int*)g,
        (__attribute__((address_space(3))) unsigned int*)l, 16, 0, 0);
}

// ---------------- weight transpose + fp32->bf16 convert ----------------
// src [K][N] fp32 row-major  ->  dst [N][K] bf16 row-major
__global__ __launch_bounds__(256) void transp_f32_bf16(
    const float* __restrict__ src, short* __restrict__ dst, int K, int N) {
    __shared__ float tile[32][33];
    int tk = blockIdx.y * 32, tn = blockIdx.x * 32;
    int tx = threadIdx.x & 31, ty = threadIdx.x >> 5;   // 32 x 8
#pragma unroll
    for (int i = 0; i < 4; i++) {
        int r = ty + i * 8;
        tile[r][tx] = src[(size_t)(tk + r) * N + tn + tx];
    }
    __syncthreads();
#pragma unroll
    for (int i = 0; i < 4; i++) {
        int r = ty + i * 8;   // n offset
        dst[(size_t)(tn + r) * K + tk + tx] = f2bf(tile[tx][r]);
    }
}

__global__ void copyv(const float* __restrict__ s, float* __restrict__ d, int n) {
    int i = blockIdx.x * blockDim.x + threadIdx.x;
    if (i < n) d[i] = s[i];
}

// ---------------- LayerNorm (fp32 in, bf16 out), one block per row (D=1024) ----------------
__global__ __launch_bounds__(256) void ln_rows(
    const float* __restrict__ x, const float* __restrict__ g,
    const float* __restrict__ bta, short* __restrict__ out) {
    int row = blockIdx.x;
    const float* xr = x + (size_t)row * D_;
    int t = threadIdx.x;
    float4 v = *(const float4*)(xr + t * 4);
    float s  = v.x + v.y + v.z + v.w;
    float s2 = v.x * v.x + v.y * v.y + v.z * v.z + v.w * v.w;
#pragma unroll
    for (int off = 1; off < 64; off <<= 1) {
        s  += __shfl_xor(s, off);
        s2 += __shfl_xor(s2, off);
    }
    __shared__ float as_[4], as2_[4];
    int wave = t >> 6, lane = t & 63;
    if (lane == 0) { as_[wave] = s; as2_[wave] = s2; }
    __syncthreads();
    s  = as_[0] + as_[1] + as_[2] + as_[3];
    s2 = as2_[0] + as2_[1] + as2_[2] + as2_[3];
    float mean = s * (1.0f / D_);
    float var  = s2 * (1.0f / D_) - mean * mean;
    float rstd = rsqrtf(var + 1e-5f);
    float4 gv = *(const float4*)(g + t * 4);
    float4 bv = *(const float4*)(bta + t * 4);
    short4 o;
    o.x = f2bf((v.x - mean) * rstd * gv.x + bv.x);
    o.y = f2bf((v.y - mean) * rstd * gv.y + bv.y);
    o.z = f2bf((v.z - mean) * rstd * gv.z + bv.z);
    o.w = f2bf((v.w - mean) * rstd * gv.w + bv.w);
    *(short4*)(out + (size_t)row * D_ + t * 4) = o;
}

// ---------------- row softmax over T_=2048 fp32, writes bf16 P in place ----------------
__global__ __launch_bounds__(256) void softmax_rows(float* __restrict__ S) {
    size_t row = blockIdx.x;
    float* sr = S + row * (size_t)T_;
    int t = threadIdx.x;
    float4 v0 = *(const float4*)(sr + t * 4);
    float4 v1 = *(const float4*)(sr + 1024 + t * 4);
    const float c = 0.03125f;   // 1/sqrt(1024)
    float vv[8] = {v0.x * c, v0.y * c, v0.z * c, v0.w * c,
                   v1.x * c, v1.y * c, v1.z * c, v1.w * c};
    float mx = -1e30f;
#pragma unroll
    for (int i = 0; i < 8; i++) mx = fmaxf(mx, vv[i]);
#pragma unroll
    for (int off = 1; off < 64; off <<= 1) mx = fmaxf(mx, __shfl_xor(mx, off));
    __shared__ float sm_[4], ss[4];
    int wave = t >> 6, lane = t & 63;
    if (lane == 0) sm_[wave] = mx;
    __syncthreads();
    mx = fmaxf(fmaxf(sm_[0], sm_[1]), fmaxf(sm_[2], sm_[3]));
    float sum = 0.f;
#pragma unroll
    for (int i = 0; i < 8; i++) { vv[i] = expf(vv[i] - mx); sum += vv[i]; }
#pragma unroll
    for (int off = 1; off < 64; off <<= 1) sum += __shfl_xor(sum, off);
    if (lane == 0) ss[wave] = sum;
    __syncthreads();
    sum = ss[0] + ss[1] + ss[2] + ss[3];
    float inv = 1.0f / sum;
    short* pr = (short*)sr;
    short4 oa, ob;
    oa.x = f2bf(vv[0] * inv); oa.y = f2bf(vv[1] * inv);
    oa.z = f2bf(vv[2] * inv); oa.w = f2bf(vv[3] * inv);
    ob.x = f2bf(vv[4] * inv); ob.y = f2bf(vv[5] * inv);
    ob.z = f2bf(vv[6] * inv); ob.w = f2bf(vv[7] * inv);
    *(short4*)(pr + t * 4) = oa;
    *(short4*)(pr + 1024 + t * 4) = ob;
}

// ---------------- 8-phase-class GEMM: C[m][n] = sum_k A[m][k]*Bt[n][k] ----------------
// 256x256 tile, BK=32, 8 waves (2Mx4N), per-wave 128x64 output (acc[8][4]).
// 4 LDS K-tile slots (128 KiB dynamic), stage K-tile t+2 while computing t.
// 2 phases per K-tile; counted vmcnt(4) once per K-tile; raw s_barrier (no drain).
// LDS read swizzle b ^= ((b>>7)&3)<<4 (conflict-free); inverse applied to global src.
#define SLOT 8192   // shorts per slot (256 rows x 32 k)
template<int BIAS_MODE, int ACT, int RES, int OUT_BF16>
__global__ __launch_bounds__(512, 2) void gemm8(
    const short* __restrict__ A, int lda, long long sA,
    const short* __restrict__ Bt, int ldb, long long sB,
    void* __restrict__ C, int ldc, long long sC,
    const float* __restrict__ bias,
    const float* __restrict__ res, int ldr, long long sR,
    int K) {
    extern __shared__ short smem_[];
    short* shA = smem_;              // 4 slots
    short* shB = smem_ + 4 * SLOT;
    int z = blockIdx.z;
    int bm = blockIdx.y * 256, bn = blockIdx.x * 256;
    const short* gA = A  + (size_t)z * sA + (size_t)bm * lda;
    const short* gB = Bt + (size_t)z * sB + (size_t)bn * ldb;
    int tid = threadIdx.x, lane = tid & 63, w = tid >> 6;
    int wr = w >> 2, wc = w & 3;

    // per-thread staging sources (global side carries the inverse swizzle;
    // LDS side stays linear: dest chunk idx = j*512+tid at byte idx*16)
    const short *pA0, *pA1, *pB0, *pB1;
    short *ldA0 = nullptr, *ldA1 = nullptr, *ldB0 = nullptr, *ldB1 = nullptr;
    {
        int o0 = tid * 16, o1 = (512 + tid) * 16;
        int s0 = o0 ^ (((o0 >> 7) & 3) << 4);
        int s1 = o1 ^ (((o1 >> 7) & 3) << 4);
        int r0 = s0 >> 6, c0 = (s0 & 63) >> 1;
        int r1 = s1 >> 6, c1 = (s1 & 63) >> 1;
        pA0 = gA + (size_t)r0 * lda + c0;
        pA1 = gA + (size_t)r1 * lda + c1;
        pB0 = gB + (size_t)r0 * ldb + c0;
        pB1 = gB + (size_t)r1 * ldb + c1;
        ldA0 = shA + tid * 8; ldA1 = shA + 4096 + tid * 8;
        ldB0 = shB + tid * 8; ldB1 = shB + 4096 + tid * 8;
    }
    // fragment ds_read byte offsets (swizzled), fixed per thread
    int aoff[8], boff[4];
#pragma unroll
    for (int f = 0; f < 8; f++) {
        int b = (wr * 128 + f * 16 + (lane & 15)) * 64 + (lane >> 4) * 16;
        aoff[f] = b ^ (((b >> 7) & 3) << 4);
    }
#pragma unroll
    for (int f = 0; f < 4; f++) {
        int b = (wc * 64 + f * 16 + (lane & 15)) * 64 + (lane >> 4) * 16;
        boff[f] = b ^ (((b >> 7) & 3) << 4);
    }

    int nk = K >> 5;
    f32x4 acc[8][4] = {};

    // prologue: stage K-tiles 0,1 into slots 0,1
    gload16(pA0,      ldA0);          gload16(pA1,      ldA1);
    gload16(pB0,      ldB0);          gload16(pB1,      ldB1);
    gload16(pA0 + 32, ldA0 + SLOT);   gload16(pA1 + 32, ldA1 + SLOT);
    gload16(pB0 + 32, ldB0 + SLOT);   gload16(pB1 + 32, ldB1 + SLOT);
    asm volatile("s_waitcnt vmcnt(4)" ::: "memory");   // slot0 landed (slot1 in flight)
    __builtin_amdgcn_s_barrier();

    for (int t = 0; t < nk; t++) {
        const char* sA_ = (const char*)(shA + (t & 3) * SLOT);
        const char* sB_ = (const char*)(shB + (t & 3) * SLOT);
        int e  = (t + 2) & 3;
        int ks = (t + 2 < nk ? t + 2 : nk - 1) * 32;   // clamped tail keeps vmcnt uniform
        // ---- phase 1: frags fr0-3 + all B; stage A(t+2) ----
        bf16x8 a0 = *(const bf16x8*)(sA_ + aoff[0]);
        bf16x8 a1 = *(const bf16x8*)(sA_ + aoff[1]);
        bf16x8 a2 = *(const bf16x8*)(sA_ + aoff[2]);
        bf16x8 a3 = *(const bf16x8*)(sA_ + aoff[3]);
        bf16x8 b0 = *(const bf16x8*)(sB_ + boff[0]);
        bf16x8 b1 = *(const bf16x8*)(sB_ + boff[1]);
        bf16x8 b2 = *(const bf16x8*)(sB_ + boff[2]);
        bf16x8 b3 = *(const bf16x8*)(sB_ + boff[3]);
        gload16(pA0 + ks, shA + e * SLOT + tid * 8);
        gload16(pA1 + ks, shA + e * SLOT + 4096 + tid * 8);
        __builtin_amdgcn_s_barrier();
        asm volatile("s_waitcnt lgkmcnt(0)" ::: "memory");
        __builtin_amdgcn_sched_barrier(0);
        __builtin_amdgcn_s_setprio(1);
#define MF(r, av) \
        acc[r][0] = __builtin_amdgcn_mfma_f32_16x16x32_bf16(av, b0, acc[r][0], 0, 0, 0); \
        acc[r][1] = __builtin_amdgcn_mfma_f32_16x16x32_bf16(av, b1, acc[r][1], 0, 0, 0); \
        acc[r][2] = __builtin_amdgcn_mfma_f32_16x16x32_bf16(av, b2, acc[r][2], 0, 0, 0); \
        acc[r][3] = __builtin_amdgcn_mfma_f32_16x16x32_bf16(av, b3, acc[r][3], 0, 0, 0);
        MF(0, a0) MF(1, a1) MF(2, a2) MF(3, a3)
        __builtin_amdgcn_s_setprio(0);
        __builtin_amdgcn_s_barrier();
        // ---- phase 2: frags fr4-7 (B reused); stage B(t+2) ----
        a0 = *(const bf16x8*)(sA_ + aoff[4]);
        a1 = *(const bf16x8*)(sA_ + aoff[5]);
        a2 = *(const bf16x8*)(sA_ + aoff[6]);
        a3 = *(const bf16x8*)(sA_ + aoff[7]);
        gload16(pB0 + ks, shB + e * SLOT + tid * 8);
        gload16(pB1 + ks, shB + e * SLOT + 4096 + tid * 8);
        asm volatile("s_waitcnt vmcnt(4)" ::: "memory");  // (t+1) slots landed; (t+2) in flight
        __builtin_amdgcn_s_barrier();
        asm volatile("s_waitcnt lgkmcnt(0)" ::: "memory");
        __builtin_amdgcn_sched_barrier(0);
        __builtin_amdgcn_s_setprio(1);
        MF(4, a0) MF(5, a1) MF(6, a2) MF(7, a3)
#undef MF
        __builtin_amdgcn_s_setprio(0);
        __builtin_amdgcn_s_barrier();
    }
    asm volatile("s_waitcnt vmcnt(0)" ::: "memory");   // drain DMA before block exit

    // epilogue: C/D layout col = lane&15, row = (lane>>4)*4 + r  [m89/m91 verified]
    size_t zc = (size_t)z * (size_t)sC;
#pragma unroll
    for (int fr = 0; fr < 8; fr++) {
#pragma unroll
        for (int fn = 0; fn < 4; fn++) {
            int col = bn + wc * 64 + fn * 16 + (lane & 15);
#pragma unroll
            for (int r = 0; r < 4; r++) {
                int row = bm + wr * 128 + fr * 16 + (lane >> 4) * 4 + r;
                float v = acc[fr][fn][r];
                if (BIAS_MODE == 1) v += bias[col];
                else if (BIAS_MODE == 2) v += bias[row];
                if (ACT == 1) v = 0.5f * v * (1.0f + erff(v * 0.70710678118654752f));
                if (RES) v += res[(size_t)z * sR + (size_t)row * ldr + col];
                if (OUT_BF16) ((short*)C)[zc + (size_t)row * ldc + col] = f2bf(v);
                else          ((float*)C)[zc + (size_t)row * ldc + col] = v;
            }
        }
    }
}

#define SHBYTES (8 * SLOT * 2)   // 131072

extern "C" void kernel_launch(void* const* d_in, const int* in_sizes, int n_in,
                              void* d_out, int out_size, void* d_ws, size_t ws_size,
                              hipStream_t stream) {
    const float* x    = (const float*)d_in[0];
    const float* ln1g = (const float*)d_in[1];
    const float* ln1b = (const float*)d_in[2];
    const float* Wq   = (const float*)d_in[3];
    const float* bq   = (const float*)d_in[4];
    const float* Wk   = (const float*)d_in[5];
    const float* bk   = (const float*)d_in[6];
    const float* Wv   = (const float*)d_in[7];
    const float* bv   = (const float*)d_in[8];
    const float* ln2g = (const float*)d_in[9];
    const float* ln2b = (const float*)d_in[10];
    const float* Win  = (const float*)d_in[11];
    const float* bin  = (const float*)d_in[12];
    const float* Wout = (const float*)d_in[13];
    const float* bout = (const float*)d_in[14];

    char* ws = (char*)d_ws;
    size_t off = 0;
    auto alloc = [&](size_t bytes) {
        void* p = ws + off;
        off += (bytes + 255) & ~(size_t)255;
        return p;
    };
    short* WqkT  = (short*)alloc((size_t)2048 * 1024 * 2);  // [2048][1024] = [Wq^T ; Wk^T]
    short* WvT   = (short*)alloc((size_t)1024 * 1024 * 2);  // [1024][1024]
    short* WinT  = (short*)alloc((size_t)4096 * 1024 * 2);  // [4096][1024]
    short* WoutT = (short*)alloc((size_t)1024 * 4096 * 2);  // [1024][4096]
    float* bqk   = (float*)alloc((size_t)2048 * 4);
    short* h     = (short*)alloc((size_t)MTOT * 1024 * 2);  // LN output (reused for LN2)
    short* QK    = (short*)alloc((size_t)MTOT * 2048 * 2);  // [8192][2048] = [Q | K]
    short* VT    = (short*)alloc((size_t)1024 * 8192 * 2);  // V^T [1024][8192]
    float* S     = (float*)alloc((size_t)4 * 2048 * 2048 * 4); // scores fp32; P bf16 + ff alias
    float* x1    = (float*)alloc((size_t)MTOT * 1024 * 4);  // x + attn_out (fp32)
    (void)ws_size; (void)in_sizes; (void)n_in; (void)out_size;

    // allow 128 KiB dynamic LDS on all gemm8 instantiations
    hipFuncSetAttribute((const void*)gemm8<1,0,0,1>, hipFuncAttributeMaxDynamicSharedMemorySize, SHBYTES);
    hipFuncSetAttribute((const void*)gemm8<2,0,0,1>, hipFuncAttributeMaxDynamicSharedMemorySize, SHBYTES);
    hipFuncSetAttribute((const void*)gemm8<0,0,0,0>, hipFuncAttributeMaxDynamicSharedMemorySize, SHBYTES);
    hipFuncSetAttribute((const void*)gemm8<0,0,1,0>, hipFuncAttributeMaxDynamicSharedMemorySize, SHBYTES);
    hipFuncSetAttribute((const void*)gemm8<1,1,0,1>, hipFuncAttributeMaxDynamicSharedMemorySize, SHBYTES);
    hipFuncSetAttribute((const void*)gemm8<1,0,1,0>, hipFuncAttributeMaxDynamicSharedMemorySize, SHBYTES);

    // --- weights -> bf16 [N][K] ---
    transp_f32_bf16<<<dim3(32, 32), 256, 0, stream>>>(Wq, WqkT, 1024, 1024);
    transp_f32_bf16<<<dim3(32, 32), 256, 0, stream>>>(Wk, WqkT + (size_t)1024 * 1024, 1024, 1024);
    transp_f32_bf16<<<dim3(32, 32), 256, 0, stream>>>(Wv, WvT, 1024, 1024);
    transp_f32_bf16<<<dim3(128, 32), 256, 0, stream>>>(Win, WinT, 1024, 4096);
    transp_f32_bf16<<<dim3(32, 128), 256, 0, stream>>>(Wout, WoutT, 4096, 1024);
    copyv<<<4, 256, 0, stream>>>(bq, bqk, 1024);
    copyv<<<4, 256, 0, stream>>>(bk, bqk + 1024, 1024);

    // --- LN1: x -> h (bf16) ---
    ln_rows<<<MTOT, 256, 0, stream>>>(x, ln1g, ln1b, h);

    // --- [Q|K] = h @ [Wq|Wk] + [bq|bk] : M=8192 N=2048 K=1024, bf16 out ---
    gemm8<1, 0, 0, 1><<<dim3(8, 32, 1), 512, SHBYTES, stream>>>(
        h, 1024, 0, WqkT, 1024, 0, QK, 2048, 0, bqk, nullptr, 0, 0, 1024);

    // --- V^T = Wv^T @ h^T + bv (per-row): M=1024 N=8192 K=1024, bf16 out ---
    gemm8<2, 0, 0, 1><<<dim3(32, 4, 1), 512, SHBYTES, stream>>>(
        WvT, 1024, 0, h, 1024, 0, VT, 8192, 0, bv, nullptr, 0, 0, 1024);

    // --- scores: per batch  S = Q_b @ K_b^T : M=N=2048 K=1024, fp32 out ---
    gemm8<0, 0, 0, 0><<<dim3(8, 8, 4), 512, SHBYTES, stream>>>(
        QK, 2048, 4194304LL, QK + 1024, 2048, 4194304LL,
        S, 2048, 4194304LL, nullptr, nullptr, 0, 0, 1024);

    // --- softmax(S/32) -> P bf16 in place (P ld = 4096 shorts) ---
    softmax_rows<<<MTOT, 256, 0, stream>>>(S);

    // --- attn_out + x: per batch  x1 = P_b @ V_b + x : M=2048 N=1024 K=2048 ---
    gemm8<0, 0, 1, 0><<<dim3(4, 8, 4), 512, SHBYTES, stream>>>(
        (short*)S, 4096, 8388608LL, VT, 8192, 2048LL,
        x1, 1024, 2097152LL, nullptr, x, 1024, 2097152LL, 2048);

    // --- LN2: x1 -> h (bf16, reuse) ---
    ln_rows<<<MTOT, 256, 0, stream>>>(x1, ln2g, ln2b, h);

    // --- FF1: ff = gelu(h @ Win + bin) : M=8192 N=4096 K=1024, bf16 out (aliases S) ---
    short* ff = (short*)S;
    gemm8<1, 1, 0, 1><<<dim3(16, 32, 1), 512, SHBYTES, stream>>>(
        h, 1024, 0, WinT, 1024, 0, ff, 4096, 0, bin, nullptr, 0, 0, 1024);

    // --- FF2: out = ff @ Wout + bout + x1 : M=8192 N=1024 K=4096, fp32 out ---
    gemm8<1, 0, 1, 0><<<dim3(4, 32, 1), 512, SHBYTES, stream>>>(
        ff, 4096, 0, WoutT, 4096, 0, (float*)d_out, 1024, 0, bout,
        x1, 1024, 0, 4096);
}

// Round 4
// 454.879 us; speedup vs baseline: 1.1822x; 1.0201x over previous
//
#include <hip/hip_runtime.h>
#include <hip/hip_bf16.h>

// Problem dims
#define B_    4
#define T_    2048
#define D_    1024
#define DH_   1024
#define DFF_  4096
#define MTOT  (B_ * T_)   // 8192 rows

using f32x4  = __attribute__((ext_vector_type(4))) float;
using bf16x8 = __attribute__((ext_vector_type(8))) short;

__device__ __forceinline__ unsigned short f2bf(float f) {
    unsigned u = __builtin_bit_cast(unsigned, f);
    u += 0x7fffu + ((u >> 16) & 1u);     // round-to-nearest-even
    return (unsigned short)(u >> 16);
}

// async global->LDS, 16B per lane; LDS dest is wave-uniform base + lane*16
__device__ __forceinline__ void gload16(const short* g, short* l) {
    __builtin_amdgcn_global_load_lds(
        (const __attribute__((address_space(1))) unsigned int*)g,
        (__attribute__((address_space(3))) unsigned int*)l, 16, 0, 0);
}

// ---------------- weight transpose + fp32->bf16 convert ----------------
// src [K][N] fp32 row-major  ->  dst [N][K] bf16 row-major
__global__ __launch_bounds__(256) void transp_f32_bf16(
    const float* __restrict__ src, short* __restrict__ dst, int K, int N) {
    __shared__ float tile[32][33];
    int tk = blockIdx.y * 32, tn = blockIdx.x * 32;
    int tx = threadIdx.x & 31, ty = threadIdx.x >> 5;   // 32 x 8
#pragma unroll
    for (int i = 0; i < 4; i++) {
        int r = ty + i * 8;
        tile[r][tx] = src[(size_t)(tk + r) * N + tn + tx];
    }
    __syncthreads();
#pragma unroll
    for (int i = 0; i < 4; i++) {
        int r = ty + i * 8;   // n offset
        dst[(size_t)(tn + r) * K + tk + tx] = f2bf(tile[tx][r]);
    }
}

__global__ void copyv(const float* __restrict__ s, float* __restrict__ d, int n) {
    int i = blockIdx.x * blockDim.x + threadIdx.x;
    if (i < n) d[i] = s[i];
}

// ---------------- LayerNorm (fp32 in, bf16 out), one block per row (D=1024) ----------------
__global__ __launch_bounds__(256) void ln_rows(
    const float* __restrict__ x, const float* __restrict__ g,
    const float* __restrict__ bta, short* __restrict__ out) {
    int row = blockIdx.x;
    const float* xr = x + (size_t)row * D_;
    int t = threadIdx.x;
    float4 v = *(const float4*)(xr + t * 4);
    float s  = v.x + v.y + v.z + v.w;
    float s2 = v.x * v.x + v.y * v.y + v.z * v.z + v.w * v.w;
#pragma unroll
    for (int off = 1; off < 64; off <<= 1) {
        s  += __shfl_xor(s, off);
        s2 += __shfl_xor(s2, off);
    }
    __shared__ float as_[4], as2_[4];
    int wave = t >> 6, lane = t & 63;
    if (lane == 0) { as_[wave] = s; as2_[wave] = s2; }
    __syncthreads();
    s  = as_[0] + as_[1] + as_[2] + as_[3];
    s2 = as2_[0] + as2_[1] + as2_[2] + as2_[3];
    float mean = s * (1.0f / D_);
    float var  = s2 * (1.0f / D_) - mean * mean;
    float rstd = rsqrtf(var + 1e-5f);
    float4 gv = *(const float4*)(g + t * 4);
    float4 bv = *(const float4*)(bta + t * 4);
    short4 o;
    o.x = f2bf((v.x - mean) * rstd * gv.x + bv.x);
    o.y = f2bf((v.y - mean) * rstd * gv.y + bv.y);
    o.z = f2bf((v.z - mean) * rstd * gv.z + bv.z);
    o.w = f2bf((v.w - mean) * rstd * gv.w + bv.w);
    *(short4*)(out + (size_t)row * D_ + t * 4) = o;
}

// ---------------- row softmax over T_=2048 fp32, writes bf16 P in place ----------------
__global__ __launch_bounds__(256) void softmax_rows(float* __restrict__ S) {
    size_t row = blockIdx.x;
    float* sr = S + row * (size_t)T_;
    int t = threadIdx.x;
    float4 v0 = *(const float4*)(sr + t * 4);
    float4 v1 = *(const float4*)(sr + 1024 + t * 4);
    const float c = 0.03125f;   // 1/sqrt(1024)
    float vv[8] = {v0.x * c, v0.y * c, v0.z * c, v0.w * c,
                   v1.x * c, v1.y * c, v1.z * c, v1.w * c};
    float mx = -1e30f;
#pragma unroll
    for (int i = 0; i < 8; i++) mx = fmaxf(mx, vv[i]);
#pragma unroll
    for (int off = 1; off < 64; off <<= 1) mx = fmaxf(mx, __shfl_xor(mx, off));
    __shared__ float sm_[4], ss[4];
    int wave = t >> 6, lane = t & 63;
    if (lane == 0) sm_[wave] = mx;
    __syncthreads();
    mx = fmaxf(fmaxf(sm_[0], sm_[1]), fmaxf(sm_[2], sm_[3]));
    float sum = 0.f;
#pragma unroll
    for (int i = 0; i < 8; i++) { vv[i] = expf(vv[i] - mx); sum += vv[i]; }
#pragma unroll
    for (int off = 1; off < 64; off <<= 1) sum += __shfl_xor(sum, off);
    if (lane == 0) ss[wave] = sum;
    __syncthreads();
    sum = ss[0] + ss[1] + ss[2] + ss[3];
    float inv = 1.0f / sum;
    short* pr = (short*)sr;
    short4 oa, ob;
    oa.x = f2bf(vv[0] * inv); oa.y = f2bf(vv[1] * inv);
    oa.z = f2bf(vv[2] * inv); oa.w = f2bf(vv[3] * inv);
    ob.x = f2bf(vv[4] * inv); ob.y = f2bf(vv[5] * inv);
    ob.z = f2bf(vv[6] * inv); ob.w = f2bf(vv[7] * inv);
    *(short4*)(pr + t * 4) = oa;
    *(short4*)(pr + 1024 + t * 4) = ob;
}

// ---------------- 8-phase-class GEMM: C[m][n] = sum_k A[m][k]*Bt[n][k] ----------------
// 256x256 tile, BK=32, 8 waves (2Mx4N), per-wave 128x64 output (acc[8][4]).
// 4 LDS K-tile slots (128 KiB dynamic), LEAD-3: stage K-tile t+3 while computing t
// (slot (t+3)&3 holds tile t-1, dead).  vmcnt(8) once per K-tile -> tile t+1 landed,
// t+2/t+3 in flight; each tile's loads issued 2 full iterations before use.
// Raw s_barrier (no drain).  LDS swizzle b ^= ((b>>7)&3)<<4; inverse on global src.
// XCD-chunked bijective block swizzle (m204) for L2 locality.
#define SLOT 8192   // shorts per slot (256 rows x 32 k)
template<int BIAS_MODE, int ACT, int RES, int OUT_BF16>
__global__ __launch_bounds__(512, 2) void gemm8(
    const short* __restrict__ A, int lda, long long sA,
    const short* __restrict__ Bt, int ldb, long long sB,
    void* __restrict__ C, int ldc, long long sC,
    const float* __restrict__ bias,
    const float* __restrict__ res, int ldr, long long sR,
    int K) {
    extern __shared__ short smem_[];
    short* shA = smem_;              // 4 slots
    short* shB = smem_ + 4 * SLOT;

    // ---- XCD-chunked bijective swizzle over the full linearized grid ----
    int gx = gridDim.x, gy = gridDim.y;
    int nwg = gx * gy * gridDim.z;
    int lid = blockIdx.x + gx * (blockIdx.y + gy * blockIdx.z);
    int q = nwg >> 3, r = nwg & 7, xcd = lid & 7, i_ = lid >> 3;
    int nid = (xcd < r ? xcd * (q + 1) : r * (q + 1) + (xcd - r) * q) + i_;
    int bx = nid % gx; int tmp_ = nid / gx; int by = tmp_ % gy; int z = tmp_ / gy;

    int bm = by * 256, bn = bx * 256;
    const short* gA = A  + (size_t)z * sA + (size_t)bm * lda;
    const short* gB = Bt + (size_t)z * sB + (size_t)bn * ldb;
    int tid = threadIdx.x, lane = tid & 63, w = tid >> 6;
    int wr = w >> 2, wc = w & 3;

    // per-thread staging sources (global side carries the inverse swizzle;
    // LDS side stays linear: dest chunk idx = j*512+tid at byte idx*16)
    const short *pA0, *pA1, *pB0, *pB1;
    short *ldA0, *ldA1, *ldB0, *ldB1;
    {
        int o0 = tid * 16, o1 = (512 + tid) * 16;
        int s0 = o0 ^ (((o0 >> 7) & 3) << 4);
        int s1 = o1 ^ (((o1 >> 7) & 3) << 4);
        int r0 = s0 >> 6, c0 = (s0 & 63) >> 1;
        int r1 = s1 >> 6, c1 = (s1 & 63) >> 1;
        pA0 = gA + (size_t)r0 * lda + c0;
        pA1 = gA + (size_t)r1 * lda + c1;
        pB0 = gB + (size_t)r0 * ldb + c0;
        pB1 = gB + (size_t)r1 * ldb + c1;
        ldA0 = shA + tid * 8; ldA1 = shA + 4096 + tid * 8;
        ldB0 = shB + tid * 8; ldB1 = shB + 4096 + tid * 8;
    }
    // fragment ds_read byte offsets (swizzled), fixed per thread
    int aoff[8], boff[4];
#pragma unroll
    for (int f = 0; f < 8; f++) {
        int b = (wr * 128 + f * 16 + (lane & 15)) * 64 + (lane >> 4) * 16;
        aoff[f] = b ^ (((b >> 7) & 3) << 4);
    }
#pragma unroll
    for (int f = 0; f < 4; f++) {
        int b = (wc * 64 + f * 16 + (lane & 15)) * 64 + (lane >> 4) * 16;
        boff[f] = b ^ (((b >> 7) & 3) << 4);
    }

    int nk = K >> 5;
    f32x4 acc[8][4] = {};

    // prologue: stage K-tiles 0,1,2 into slots 0,1,2  (nk >= 3 for all our shapes)
#pragma unroll
    for (int s = 0; s < 3; s++) {
        gload16(pA0 + s * 32, ldA0 + s * SLOT);  gload16(pA1 + s * 32, ldA1 + s * SLOT);
        gload16(pB0 + s * 32, ldB0 + s * SLOT);  gload16(pB1 + s * 32, ldB1 + s * SLOT);
    }
    asm volatile("s_waitcnt vmcnt(8)" ::: "memory");   // slot0 landed; 1,2 in flight
    __builtin_amdgcn_s_barrier();

    for (int t = 0; t < nk; t++) {
        const char* sA_ = (const char*)(shA + (t & 3) * SLOT);
        const char* sB_ = (const char*)(shB + (t & 3) * SLOT);
        int e  = (t + 3) & 3;
        int ks = (t + 3 < nk ? t + 3 : nk - 1) * 32;   // clamped tail keeps vmcnt uniform
        // ---- phase 1: frags fr0-3 + all B; stage A(t+3) ----
        bf16x8 a0 = *(const bf16x8*)(sA_ + aoff[0]);
        bf16x8 a1 = *(const bf16x8*)(sA_ + aoff[1]);
        bf16x8 a2 = *(const bf16x8*)(sA_ + aoff[2]);
        bf16x8 a3 = *(const bf16x8*)(sA_ + aoff[3]);
        bf16x8 b0 = *(const bf16x8*)(sB_ + boff[0]);
        bf16x8 b1 = *(const bf16x8*)(sB_ + boff[1]);
        bf16x8 b2 = *(const bf16x8*)(sB_ + boff[2]);
        bf16x8 b3 = *(const bf16x8*)(sB_ + boff[3]);
        gload16(pA0 + ks, shA + e * SLOT + tid * 8);
        gload16(pA1 + ks, shA + e * SLOT + 4096 + tid * 8);
        __builtin_amdgcn_s_barrier();
        asm volatile("s_waitcnt lgkmcnt(0)" ::: "memory");
        __builtin_amdgcn_sched_barrier(0);
        __builtin_amdgcn_s_setprio(1);
#define MF(r_, av) \
        acc[r_][0] = __builtin_amdgcn_mfma_f32_16x16x32_bf16(av, b0, acc[r_][0], 0, 0, 0); \
        acc[r_][1] = __builtin_amdgcn_mfma_f32_16x16x32_bf16(av, b1, acc[r_][1], 0, 0, 0); \
        acc[r_][2] = __builtin_amdgcn_mfma_f32_16x16x32_bf16(av, b2, acc[r_][2], 0, 0, 0); \
        acc[r_][3] = __builtin_amdgcn_mfma_f32_16x16x32_bf16(av, b3, acc[r_][3], 0, 0, 0);
        MF(0, a0) MF(1, a1) MF(2, a2) MF(3, a3)
        __builtin_amdgcn_s_setprio(0);
        __builtin_amdgcn_s_barrier();
        // ---- phase 2: frags fr4-7 (B reused); stage B(t+3) ----
        a0 = *(const bf16x8*)(sA_ + aoff[4]);
        a1 = *(const bf16x8*)(sA_ + aoff[5]);
        a2 = *(const bf16x8*)(sA_ + aoff[6]);
        a3 = *(const bf16x8*)(sA_ + aoff[7]);
        gload16(pB0 + ks, shB + e * SLOT + tid * 8);
        gload16(pB1 + ks, shB + e * SLOT + 4096 + tid * 8);
        asm volatile("s_waitcnt vmcnt(8)" ::: "memory");  // t+1 landed; t+2,t+3 in flight
        __builtin_amdgcn_s_barrier();
        asm volatile("s_waitcnt lgkmcnt(0)" ::: "memory");
        __builtin_amdgcn_sched_barrier(0);
        __builtin_amdgcn_s_setprio(1);
        MF(4, a0) MF(5, a1) MF(6, a2) MF(7, a3)
#undef MF
        __builtin_amdgcn_s_setprio(0);
        __builtin_amdgcn_s_barrier();
    }
    asm volatile("s_waitcnt vmcnt(0)" ::: "memory");   // drain DMA before block exit

    // epilogue: C/D layout col = lane&15, row = (lane>>4)*4 + r  [m89/m91 verified]
    size_t zc = (size_t)z * (size_t)sC;
#pragma unroll
    for (int fr = 0; fr < 8; fr++) {
#pragma unroll
        for (int fn = 0; fn < 4; fn++) {
            int col = bn + wc * 64 + fn * 16 + (lane & 15);
#pragma unroll
            for (int r_ = 0; r_ < 4; r_++) {
                int row = bm + wr * 128 + fr * 16 + (lane >> 4) * 4 + r_;
                float v = acc[fr][fn][r_];
                if (BIAS_MODE == 1) v += bias[col];
                else if (BIAS_MODE == 2) v += bias[row];
                if (ACT == 1) v = 0.5f * v * (1.0f + erff(v * 0.70710678118654752f));
                if (RES) v += res[(size_t)z * sR + (size_t)row * ldr + col];
                if (OUT_BF16) ((short*)C)[zc + (size_t)row * ldc + col] = f2bf(v);
                else          ((float*)C)[zc + (size_t)row * ldc + col] = v;
            }
        }
    }
}

#define SHBYTES (8 * SLOT * 2)   // 131072

extern "C" void kernel_launch(void* const* d_in, const int* in_sizes, int n_in,
                              void* d_out, int out_size, void* d_ws, size_t ws_size,
                              hipStream_t stream) {
    const float* x    = (const float*)d_in[0];
    const float* ln1g = (const float*)d_in[1];
    const float* ln1b = (const float*)d_in[2];
    const float* Wq   = (const float*)d_in[3];
    const float* bq   = (const float*)d_in[4];
    const float* Wk   = (const float*)d_in[5];
    const float* bk   = (const float*)d_in[6];
    const float* Wv   = (const float*)d_in[7];
    const float* bv   = (const float*)d_in[8];
    const float* ln2g = (const float*)d_in[9];
    const float* ln2b = (const float*)d_in[10];
    const float* Win  = (const float*)d_in[11];
    const float* bin  = (const float*)d_in[12];
    const float* Wout = (const float*)d_in[13];
    const float* bout = (const float*)d_in[14];

    char* ws = (char*)d_ws;
    size_t off = 0;
    auto alloc = [&](size_t bytes) {
        void* p = ws + off;
        off += (bytes + 255) & ~(size_t)255;
        return p;
    };
    short* WqkT  = (short*)alloc((size_t)2048 * 1024 * 2);  // [2048][1024] = [Wq^T ; Wk^T]
    short* WvT   = (short*)alloc((size_t)1024 * 1024 * 2);  // [1024][1024]
    short* WinT  = (short*)alloc((size_t)4096 * 1024 * 2);  // [4096][1024]
    short* WoutT = (short*)alloc((size_t)1024 * 4096 * 2);  // [1024][4096]
    float* bqk   = (float*)alloc((size_t)2048 * 4);
    short* h     = (short*)alloc((size_t)MTOT * 1024 * 2);  // LN output (reused for LN2)
    short* QK    = (short*)alloc((size_t)MTOT * 2048 * 2);  // [8192][2048] = [Q | K]
    short* VT    = (short*)alloc((size_t)1024 * 8192 * 2);  // V^T [1024][8192]
    float* S     = (float*)alloc((size_t)4 * 2048 * 2048 * 4); // scores fp32; P bf16 + ff alias
    float* x1    = (float*)alloc((size_t)MTOT * 1024 * 4);  // x + attn_out (fp32)
    (void)ws_size; (void)in_sizes; (void)n_in; (void)out_size;

    // allow 128 KiB dynamic LDS on all gemm8 instantiations
    hipFuncSetAttribute((const void*)gemm8<1,0,0,1>, hipFuncAttributeMaxDynamicSharedMemorySize, SHBYTES);
    hipFuncSetAttribute((const void*)gemm8<2,0,0,1>, hipFuncAttributeMaxDynamicSharedMemorySize, SHBYTES);
    hipFuncSetAttribute((const void*)gemm8<0,0,0,0>, hipFuncAttributeMaxDynamicSharedMemorySize, SHBYTES);
    hipFuncSetAttribute((const void*)gemm8<0,0,1,0>, hipFuncAttributeMaxDynamicSharedMemorySize, SHBYTES);
    hipFuncSetAttribute((const void*)gemm8<1,1,0,1>, hipFuncAttributeMaxDynamicSharedMemorySize, SHBYTES);
    hipFuncSetAttribute((const void*)gemm8<1,0,1,0>, hipFuncAttributeMaxDynamicSharedMemorySize, SHBYTES);

    // --- weights -> bf16 [N][K] ---
    transp_f32_bf16<<<dim3(32, 32), 256, 0, stream>>>(Wq, WqkT, 1024, 1024);
    transp_f32_bf16<<<dim3(32, 32), 256, 0, stream>>>(Wk, WqkT + (size_t)1024 * 1024, 1024, 1024);
    transp_f32_bf16<<<dim3(32, 32), 256, 0, stream>>>(Wv, WvT, 1024, 1024);
    transp_f32_bf16<<<dim3(128, 32), 256, 0, stream>>>(Win, WinT, 1024, 4096);
    transp_f32_bf16<<<dim3(32, 128), 256, 0, stream>>>(Wout, WoutT, 4096, 1024);
    copyv<<<4, 256, 0, stream>>>(bq, bqk, 1024);
    copyv<<<4, 256, 0, stream>>>(bk, bqk + 1024, 1024);

    // --- LN1: x -> h (bf16) ---
    ln_rows<<<MTOT, 256, 0, stream>>>(x, ln1g, ln1b, h);

    // --- [Q|K] = h @ [Wq|Wk] + [bq|bk] : M=8192 N=2048 K=1024, bf16 out ---
    gemm8<1, 0, 0, 1><<<dim3(8, 32, 1), 512, SHBYTES, stream>>>(
        h, 1024, 0, WqkT, 1024, 0, QK, 2048, 0, bqk, nullptr, 0, 0, 1024);

    // --- V^T = Wv^T @ h^T + bv (per-row): M=1024 N=8192 K=1024, bf16 out ---
    gemm8<2, 0, 0, 1><<<dim3(32, 4, 1), 512, SHBYTES, stream>>>(
        WvT, 1024, 0, h, 1024, 0, VT, 8192, 0, bv, nullptr, 0, 0, 1024);

    // --- scores: per batch  S = Q_b @ K_b^T : M=N=2048 K=1024, fp32 out ---
    gemm8<0, 0, 0, 0><<<dim3(8, 8, 4), 512, SHBYTES, stream>>>(
        QK, 2048, 4194304LL, QK + 1024, 2048, 4194304LL,
        S, 2048, 4194304LL, nullptr, nullptr, 0, 0, 1024);

    // --- softmax(S/32) -> P bf16 in place (P ld = 4096 shorts) ---
    softmax_rows<<<MTOT, 256, 0, stream>>>(S);

    // --- attn_out + x: per batch  x1 = P_b @ V_b + x : M=2048 N=1024 K=2048 ---
    gemm8<0, 0, 1, 0><<<dim3(4, 8, 4), 512, SHBYTES, stream>>>(
        (short*)S, 4096, 8388608LL, VT, 8192, 2048LL,
        x1, 1024, 2097152LL, nullptr, x, 1024, 2097152LL, 2048);

    // --- LN2: x1 -> h (bf16, reuse) ---
    ln_rows<<<MTOT, 256, 0, stream>>>(x1, ln2g, ln2b, h);

    // --- FF1: ff = gelu(h @ Win + bin) : M=8192 N=4096 K=1024, bf16 out (aliases S) ---
    short* ff = (short*)S;
    gemm8<1, 1, 0, 1><<<dim3(16, 32, 1), 512, SHBYTES, stream>>>(
        h, 1024, 0, WinT, 1024, 0, ff, 4096, 0, bin, nullptr, 0, 0, 1024);

    // --- FF2: out = ff @ Wout + bout + x1 : M=8192 N=1024 K=4096, fp32 out ---
    gemm8<1, 0, 1, 0><<<dim3(4, 32, 1), 512, SHBYTES, stream>>>(
        ff, 4096, 0, WoutT, 4096, 0, (float*)d_out, 1024, 0, bout,
        x1, 1024, 0, 4096);
}

// Round 5
// 432.749 us; speedup vs baseline: 1.2426x; 1.0511x over previous
//
#include <hip/hip_runtime.h>
#include <hip/hip_bf16.h>

// Problem dims
#define B_    4
#define T_    2048
#define D_    1024
#define DH_   1024
#define DFF_  4096
#define MTOT  (B_ * T_)   // 8192 rows

using f32x4  = __attribute__((ext_vector_type(4))) float;
using bf16x8 = __attribute__((ext_vector_type(8))) short;

__device__ __forceinline__ unsigned short f2bf(float f) {
    unsigned u = __builtin_bit_cast(unsigned, f);
    u += 0x7fffu + ((u >> 16) & 1u);     // round-to-nearest-even
    return (unsigned short)(u >> 16);
}

// async global->LDS, 16B per lane; LDS dest is wave-uniform base + lane*16
__device__ __forceinline__ void gload16(const short* g, short* l) {
    __builtin_amdgcn_global_load_lds(
        (const __attribute__((address_space(1))) unsigned int*)g,
        (__attribute__((address_space(3))) unsigned int*)l, 16, 0, 0);
}

// ---------------- weight transpose + fp32->bf16 convert ----------------
// src [K][N] fp32 row-major  ->  dst [N][K] bf16 row-major
__global__ __launch_bounds__(256) void transp_f32_bf16(
    const float* __restrict__ src, short* __restrict__ dst, int K, int N) {
    __shared__ float tile[32][33];
    int tk = blockIdx.y * 32, tn = blockIdx.x * 32;
    int tx = threadIdx.x & 31, ty = threadIdx.x >> 5;   // 32 x 8
#pragma unroll
    for (int i = 0; i < 4; i++) {
        int r = ty + i * 8;
        tile[r][tx] = src[(size_t)(tk + r) * N + tn + tx];
    }
    __syncthreads();
#pragma unroll
    for (int i = 0; i < 4; i++) {
        int r = ty + i * 8;   // n offset
        dst[(size_t)(tn + r) * K + tk + tx] = f2bf(tile[tx][r]);
    }
}

__global__ void copyv(const float* __restrict__ s, float* __restrict__ d, int n) {
    int i = blockIdx.x * blockDim.x + threadIdx.x;
    if (i < n) d[i] = s[i];
}

// ---------------- LayerNorm (fp32 in, bf16 out), one block per row (D=1024) ----------------
__global__ __launch_bounds__(256) void ln_rows(
    const float* __restrict__ x, const float* __restrict__ g,
    const float* __restrict__ bta, short* __restrict__ out) {
    int row = blockIdx.x;
    const float* xr = x + (size_t)row * D_;
    int t = threadIdx.x;
    float4 v = *(const float4*)(xr + t * 4);
    float s  = v.x + v.y + v.z + v.w;
    float s2 = v.x * v.x + v.y * v.y + v.z * v.z + v.w * v.w;
#pragma unroll
    for (int off = 1; off < 64; off <<= 1) {
        s  += __shfl_xor(s, off);
        s2 += __shfl_xor(s2, off);
    }
    __shared__ float as_[4], as2_[4];
    int wave = t >> 6, lane = t & 63;
    if (lane == 0) { as_[wave] = s; as2_[wave] = s2; }
    __syncthreads();
    s  = as_[0] + as_[1] + as_[2] + as_[3];
    s2 = as2_[0] + as2_[1] + as2_[2] + as2_[3];
    float mean = s * (1.0f / D_);
    float var  = s2 * (1.0f / D_) - mean * mean;
    float rstd = rsqrtf(var + 1e-5f);
    float4 gv = *(const float4*)(g + t * 4);
    float4 bv = *(const float4*)(bta + t * 4);
    short4 o;
    o.x = f2bf((v.x - mean) * rstd * gv.x + bv.x);
    o.y = f2bf((v.y - mean) * rstd * gv.y + bv.y);
    o.z = f2bf((v.z - mean) * rstd * gv.z + bv.z);
    o.w = f2bf((v.w - mean) * rstd * gv.w + bv.w);
    *(short4*)(out + (size_t)row * D_ + t * 4) = o;
}

// ---------------- row softmax over T_=2048 fp32, writes bf16 P in place ----------------
__global__ __launch_bounds__(256) void softmax_rows(float* __restrict__ S) {
    size_t row = blockIdx.x;
    float* sr = S + row * (size_t)T_;
    int t = threadIdx.x;
    float4 v0 = *(const float4*)(sr + t * 4);
    float4 v1 = *(const float4*)(sr + 1024 + t * 4);
    const float c = 0.03125f;   // 1/sqrt(1024)
    float vv[8] = {v0.x * c, v0.y * c, v0.z * c, v0.w * c,
                   v1.x * c, v1.y * c, v1.z * c, v1.w * c};
    float mx = -1e30f;
#pragma unroll
    for (int i = 0; i < 8; i++) mx = fmaxf(mx, vv[i]);
#pragma unroll
    for (int off = 1; off < 64; off <<= 1) mx = fmaxf(mx, __shfl_xor(mx, off));
    __shared__ float sm_[4], ss[4];
    int wave = t >> 6, lane = t & 63;
    if (lane == 0) sm_[wave] = mx;
    __syncthreads();
    mx = fmaxf(fmaxf(sm_[0], sm_[1]), fmaxf(sm_[2], sm_[3]));
    float sum = 0.f;
#pragma unroll
    for (int i = 0; i < 8; i++) { vv[i] = expf(vv[i] - mx); sum += vv[i]; }
#pragma unroll
    for (int off = 1; off < 64; off <<= 1) sum += __shfl_xor(sum, off);
    if (lane == 0) ss[wave] = sum;
    __syncthreads();
    sum = ss[0] + ss[1] + ss[2] + ss[3];
    float inv = 1.0f / sum;
    short* pr = (short*)sr;
    short4 oa, ob;
    oa.x = f2bf(vv[0] * inv); oa.y = f2bf(vv[1] * inv);
    oa.z = f2bf(vv[2] * inv); oa.w = f2bf(vv[3] * inv);
    ob.x = f2bf(vv[4] * inv); ob.y = f2bf(vv[5] * inv);
    ob.z = f2bf(vv[6] * inv); ob.w = f2bf(vv[7] * inv);
    *(short4*)(pr + t * 4) = oa;
    *(short4*)(pr + 1024 + t * 4) = ob;
}

// ---------------- 4-phase BK=64 GEMM: C[m][n] = sum_k A[m][k]*Bt[n][k] ----------------
// 256x256 tile, BK=64, 8 waves (2Mx4N), per-wave 128x64 out (acc[8][4]).
// 2 LDS dbuf slots (128 KiB). Per K-tile: 4 phases x {ds_read subtile; 2 gloads;
// barrier; lgkm(0); setprio(1); 16 MFMA; setprio(0); barrier}. Staggered counted
// vmcnt(2) at ends of P1 and P4 (ledger-verified; never drains mid-loop).
// Swizzle: byte ^= ((row&7)<<4) within each 128B row; inverse on global src,
// linear LDS dest. Supertile+XCD-chunked block order for L2 locality.
#define TILE_SH 16384   // shorts per slot (256 rows x 64 k)
template<int BIAS_MODE, int ACT, int RES, int OUT_BF16>
__global__ __launch_bounds__(512, 2) void gemm8(
    const short* __restrict__ A, int lda, long long sA,
    const short* __restrict__ Bt, int ldb, long long sB,
    void* __restrict__ C, int ldc, long long sC,
    const float* __restrict__ bias,
    const float* __restrict__ res, int ldr, long long sR,
    int K) {
    extern __shared__ short smem_[];
    short* shA = smem_;                 // 2 slots x 16384 shorts
    short* shB = smem_ + 2 * TILE_SH;

    // ---- XCD-chunked bijective swizzle + 4-wide bn supertile strips ----
    int gx = gridDim.x, gy = gridDim.y;
    int n2d = gx * gy;
    int nwg = n2d * gridDim.z;
    int lid = blockIdx.x + gx * (blockIdx.y + gy * blockIdx.z);
    int q = nwg >> 3, rq = nwg & 7, xcd = lid & 7, i_ = lid >> 3;
    int nid = (xcd < rq ? xcd * (q + 1) : rq * (q + 1) + (xcd - rq) * q) + i_;
    int z = nid / n2d, r2d = nid % n2d;
    int sw = gy << 2;                          // requires gx % 4 == 0 (all grids)
    int strip = r2d / sw, rr = r2d % sw;
    int by = rr >> 2, bx = (strip << 2) + (rr & 3);

    int bm = by * 256, bn = bx * 256;
    const short* gA = A  + (size_t)z * sA + (size_t)bm * lda;
    const short* gB = Bt + (size_t)z * sB + (size_t)bn * ldb;
    int tid = threadIdx.x, lane = tid & 63, w = tid >> 6;
    int wr = w >> 2, wc = w & 3;

    // staging: 8KB chunk c covers rows c*64..c*64+63; lane handles 16B of a
    // 128B row; global col carries the inverse swizzle, LDS dest linear.
    int rbase = tid >> 3;                                    // 0..63
    int colb  = ((tid << 4) & 127) ^ ((rbase & 7) << 4);     // swizzled byte col
    int col   = colb >> 1;                                   // shorts
    const short* pA[4]; const short* pB[4];
#pragma unroll
    for (int c = 0; c < 4; c++) {
        pA[c] = gA + (size_t)(c * 64 + rbase) * lda + col;
        pB[c] = gB + (size_t)(c * 64 + rbase) * ldb + col;
    }
    // fragment ds_read byte offsets (k0 slice); k1 = off ^ 64
    int aoff[8], boff[4];
#pragma unroll
    for (int f = 0; f < 8; f++) {
        int row = wr * 128 + f * 16 + (lane & 15);
        aoff[f] = row * 128 + ((((lane >> 4) * 16)) ^ ((row & 7) << 4));
    }
#pragma unroll
    for (int f = 0; f < 4; f++) {
        int row = wc * 64 + f * 16 + (lane & 15);
        boff[f] = row * 128 + ((((lane >> 4) * 16)) ^ ((row & 7) << 4));
    }

    int nk = K >> 6;
    f32x4 acc[8][4] = {};

    // prologue: tile 0 -> slot 0 (8 chunks), drain once
#pragma unroll
    for (int c = 0; c < 4; c++) {
        gload16(pA[c], shA + c * 4096 + tid * 8);
        gload16(pB[c], shB + c * 4096 + tid * 8);
    }
    asm volatile("s_waitcnt vmcnt(0)" ::: "memory");
    __builtin_amdgcn_s_barrier();

#define MF(r_, av) \
    acc[r_][0] = __builtin_amdgcn_mfma_f32_16x16x32_bf16(av, b0, acc[r_][0], 0, 0, 0); \
    acc[r_][1] = __builtin_amdgcn_mfma_f32_16x16x32_bf16(av, b1, acc[r_][1], 0, 0, 0); \
    acc[r_][2] = __builtin_amdgcn_mfma_f32_16x16x32_bf16(av, b2, acc[r_][2], 0, 0, 0); \
    acc[r_][3] = __builtin_amdgcn_mfma_f32_16x16x32_bf16(av, b3, acc[r_][3], 0, 0, 0);

    for (int t = 0; t < nk; t++) {
        const char* sA_ = (const char*)(shA + (t & 1) * TILE_SH);
        const char* sB_ = (const char*)(shB + (t & 1) * TILE_SH);
        short* wA = shA + ((t + 1) & 1) * TILE_SH;
        short* wB = shB + ((t + 1) & 1) * TILE_SH;
        int ks = (t + 1 < nk ? t + 1 : nk - 1) << 6;   // clamped tail, uniform vmcnt

        // ---- P1: m0-3 x k0 ; stage A-c0, A-c2 of tile t+1 ----
        bf16x8 a0 = *(const bf16x8*)(sA_ + aoff[0]);
        bf16x8 a1 = *(const bf16x8*)(sA_ + aoff[1]);
        bf16x8 a2 = *(const bf16x8*)(sA_ + aoff[2]);
        bf16x8 a3 = *(const bf16x8*)(sA_ + aoff[3]);
        bf16x8 b0 = *(const bf16x8*)(sB_ + boff[0]);
        bf16x8 b1 = *(const bf16x8*)(sB_ + boff[1]);
        bf16x8 b2 = *(const bf16x8*)(sB_ + boff[2]);
        bf16x8 b3 = *(const bf16x8*)(sB_ + boff[3]);
        gload16(pA[0] + ks, wA + tid * 8);
        gload16(pA[2] + ks, wA + 2 * 4096 + tid * 8);
        __builtin_amdgcn_s_barrier();
        asm volatile("s_waitcnt lgkmcnt(0)" ::: "memory");
        __builtin_amdgcn_s_setprio(1);
        MF(0, a0) MF(1, a1) MF(2, a2) MF(3, a3)
        __builtin_amdgcn_s_setprio(0);
        asm volatile("s_waitcnt vmcnt(2)" ::: "memory");  // A-c1,c3(t) landed (for P2)
        __builtin_amdgcn_s_barrier();

        // ---- P2: m4-7 x k0 (B regs reused) ; stage B-c0, B-c1 ----
        a0 = *(const bf16x8*)(sA_ + aoff[4]);
        a1 = *(const bf16x8*)(sA_ + aoff[5]);
        a2 = *(const bf16x8*)(sA_ + aoff[6]);
        a3 = *(const bf16x8*)(sA_ + aoff[7]);
        gload16(pB[0] + ks, wB + tid * 8);
        gload16(pB[1] + ks, wB + 4096 + tid * 8);
        __builtin_amdgcn_s_barrier();
        asm volatile("s_waitcnt lgkmcnt(0)" ::: "memory");
        __builtin_amdgcn_s_setprio(1);
        MF(4, a0) MF(5, a1) MF(6, a2) MF(7, a3)
        __builtin_amdgcn_s_setprio(0);
        __builtin_amdgcn_s_barrier();

        // ---- P3: m0-3 x k1 ; stage B-c2, B-c3 ----
        a0 = *(const bf16x8*)(sA_ + (aoff[0] ^ 64));
        a1 = *(const bf16x8*)(sA_ + (aoff[1] ^ 64));
        a2 = *(const bf16x8*)(sA_ + (aoff[2] ^ 64));
        a3 = *(const bf16x8*)(sA_ + (aoff[3] ^ 64));
        b0 = *(const bf16x8*)(sB_ + (boff[0] ^ 64));
        b1 = *(const bf16x8*)(sB_ + (boff[1] ^ 64));
        b2 = *(const bf16x8*)(sB_ + (boff[2] ^ 64));
        b3 = *(const bf16x8*)(sB_ + (boff[3] ^ 64));
        gload16(pB[2] + ks, wB + 2 * 4096 + tid * 8);
        gload16(pB[3] + ks, wB + 3 * 4096 + tid * 8);
        __builtin_amdgcn_s_barrier();
        asm volatile("s_waitcnt lgkmcnt(0)" ::: "memory");
        __builtin_amdgcn_s_setprio(1);
        MF(0, a0) MF(1, a1) MF(2, a2) MF(3, a3)
        __builtin_amdgcn_s_setprio(0);
        __builtin_amdgcn_s_barrier();

        // ---- P4: m4-7 x k1 ; stage A-c1, A-c3 ----
        a0 = *(const bf16x8*)(sA_ + (aoff[4] ^ 64));
        a1 = *(const bf16x8*)(sA_ + (aoff[5] ^ 64));
        a2 = *(const bf16x8*)(sA_ + (aoff[6] ^ 64));
        a3 = *(const bf16x8*)(sA_ + (aoff[7] ^ 64));
        gload16(pA[1] + ks, wA + 4096 + tid * 8);
        gload16(pA[3] + ks, wA + 3 * 4096 + tid * 8);
        __builtin_amdgcn_s_barrier();
        asm volatile("s_waitcnt lgkmcnt(0)" ::: "memory");
        __builtin_amdgcn_s_setprio(1);
        MF(4, a0) MF(5, a1) MF(6, a2) MF(7, a3)
        __builtin_amdgcn_s_setprio(0);
        asm volatile("s_waitcnt vmcnt(2)" ::: "memory");  // 6 chunks of t+1 landed
        __builtin_amdgcn_s_barrier();
    }
#undef MF
    asm volatile("s_waitcnt vmcnt(0)" ::: "memory");   // drain DMA before epilogue

    // epilogue: C/D layout col = lane&15, row = (lane>>4)*4 + r  [m89/m91 verified]
    size_t zc = (size_t)z * (size_t)sC;
#pragma unroll
    for (int fr = 0; fr < 8; fr++) {
#pragma unroll
        for (int fn = 0; fn < 4; fn++) {
            int colc = bn + wc * 64 + fn * 16 + (lane & 15);
#pragma unroll
            for (int r_ = 0; r_ < 4; r_++) {
                int row = bm + wr * 128 + fr * 16 + (lane >> 4) * 4 + r_;
                float v = acc[fr][fn][r_];
                if (BIAS_MODE == 1) v += bias[colc];
                else if (BIAS_MODE == 2) v += bias[row];
                if (ACT == 1) v = 0.5f * v * (1.0f + erff(v * 0.70710678118654752f));
                if (RES) v += res[(size_t)z * sR + (size_t)row * ldr + colc];
                if (OUT_BF16) ((short*)C)[zc + (size_t)row * ldc + colc] = f2bf(v);
                else          ((float*)C)[zc + (size_t)row * ldc + colc] = v;
            }
        }
    }
}

#define SHBYTES (4 * TILE_SH * 2)   // 131072

extern "C" void kernel_launch(void* const* d_in, const int* in_sizes, int n_in,
                              void* d_out, int out_size, void* d_ws, size_t ws_size,
                              hipStream_t stream) {
    const float* x    = (const float*)d_in[0];
    const float* ln1g = (const float*)d_in[1];
    const float* ln1b = (const float*)d_in[2];
    const float* Wq   = (const float*)d_in[3];
    const float* bq   = (const float*)d_in[4];
    const float* Wk   = (const float*)d_in[5];
    const float* bk   = (const float*)d_in[6];
    const float* Wv   = (const float*)d_in[7];
    const float* bv   = (const float*)d_in[8];
    const float* ln2g = (const float*)d_in[9];
    const float* ln2b = (const float*)d_in[10];
    const float* Win  = (const float*)d_in[11];
    const float* bin  = (const float*)d_in[12];
    const float* Wout = (const float*)d_in[13];
    const float* bout = (const float*)d_in[14];

    char* ws = (char*)d_ws;
    size_t off = 0;
    auto alloc = [&](size_t bytes) {
        void* p = ws + off;
        off += (bytes + 255) & ~(size_t)255;
        return p;
    };
    short* WqkT  = (short*)alloc((size_t)2048 * 1024 * 2);  // [2048][1024] = [Wq^T ; Wk^T]
    short* WvT   = (short*)alloc((size_t)1024 * 1024 * 2);  // [1024][1024]
    short* WinT  = (short*)alloc((size_t)4096 * 1024 * 2);  // [4096][1024]
    short* WoutT = (short*)alloc((size_t)1024 * 4096 * 2);  // [1024][4096]
    float* bqk   = (float*)alloc((size_t)2048 * 4);
    short* h     = (short*)alloc((size_t)MTOT * 1024 * 2);  // LN output (reused for LN2)
    short* QK    = (short*)alloc((size_t)MTOT * 2048 * 2);  // [8192][2048] = [Q | K]
    short* VT    = (short*)alloc((size_t)1024 * 8192 * 2);  // V^T [1024][8192]
    float* S     = (float*)alloc((size_t)4 * 2048 * 2048 * 4); // scores fp32; P bf16 + ff alias
    float* x1    = (float*)alloc((size_t)MTOT * 1024 * 4);  // x + attn_out (fp32)
    (void)ws_size; (void)in_sizes; (void)n_in; (void)out_size;

    // allow 128 KiB dynamic LDS on all gemm8 instantiations
    hipFuncSetAttribute((const void*)gemm8<1,0,0,1>, hipFuncAttributeMaxDynamicSharedMemorySize, SHBYTES);
    hipFuncSetAttribute((const void*)gemm8<2,0,0,1>, hipFuncAttributeMaxDynamicSharedMemorySize, SHBYTES);
    hipFuncSetAttribute((const void*)gemm8<0,0,0,0>, hipFuncAttributeMaxDynamicSharedMemorySize, SHBYTES);
    hipFuncSetAttribute((const void*)gemm8<0,0,1,0>, hipFuncAttributeMaxDynamicSharedMemorySize, SHBYTES);
    hipFuncSetAttribute((const void*)gemm8<1,1,0,1>, hipFuncAttributeMaxDynamicSharedMemorySize, SHBYTES);
    hipFuncSetAttribute((const void*)gemm8<1,0,1,0>, hipFuncAttributeMaxDynamicSharedMemorySize, SHBYTES);

    // --- weights -> bf16 [N][K] ---
    transp_f32_bf16<<<dim3(32, 32), 256, 0, stream>>>(Wq, WqkT, 1024, 1024);
    transp_f32_bf16<<<dim3(32, 32), 256, 0, stream>>>(Wk, WqkT + (size_t)1024 * 1024, 1024, 1024);
    transp_f32_bf16<<<dim3(32, 32), 256, 0, stream>>>(Wv, WvT, 1024, 1024);
    transp_f32_bf16<<<dim3(128, 32), 256, 0, stream>>>(Win, WinT, 1024, 4096);
    transp_f32_bf16<<<dim3(32, 128), 256, 0, stream>>>(Wout, WoutT, 4096, 1024);
    copyv<<<4, 256, 0, stream>>>(bq, bqk, 1024);
    copyv<<<4, 256, 0, stream>>>(bk, bqk + 1024, 1024);

    // --- LN1: x -> h (bf16) ---
    ln_rows<<<MTOT, 256, 0, stream>>>(x, ln1g, ln1b, h);

    // --- [Q|K] = h @ [Wq|Wk] + [bq|bk] : M=8192 N=2048 K=1024, bf16 out ---
    gemm8<1, 0, 0, 1><<<dim3(8, 32, 1), 512, SHBYTES, stream>>>(
        h, 1024, 0, WqkT, 1024, 0, QK, 2048, 0, bqk, nullptr, 0, 0, 1024);

    // --- V^T = Wv^T @ h^T + bv (per-row): M=1024 N=8192 K=1024, bf16 out ---
    gemm8<2, 0, 0, 1><<<dim3(32, 4, 1), 512, SHBYTES, stream>>>(
        WvT, 1024, 0, h, 1024, 0, VT, 8192, 0, bv, nullptr, 0, 0, 1024);

    // --- scores: per batch  S = Q_b @ K_b^T : M=N=2048 K=1024, fp32 out ---
    gemm8<0, 0, 0, 0><<<dim3(8, 8, 4), 512, SHBYTES, stream>>>(
        QK, 2048, 4194304LL, QK + 1024, 2048, 4194304LL,
        S, 2048, 4194304LL, nullptr, nullptr, 0, 0, 1024);

    // --- softmax(S/32) -> P bf16 in place (P ld = 4096 shorts) ---
    softmax_rows<<<MTOT, 256, 0, stream>>>(S);

    // --- attn_out + x: per batch  x1 = P_b @ V_b + x : M=2048 N=1024 K=2048 ---
    gemm8<0, 0, 1, 0><<<dim3(4, 8, 4), 512, SHBYTES, stream>>>(
        (short*)S, 4096, 8388608LL, VT, 8192, 2048LL,
        x1, 1024, 2097152LL, nullptr, x, 1024, 2097152LL, 2048);

    // --- LN2: x1 -> h (bf16, reuse) ---
    ln_rows<<<MTOT, 256, 0, stream>>>(x1, ln2g, ln2b, h);

    // --- FF1: ff = gelu(h @ Win + bin) : M=8192 N=4096 K=1024, bf16 out (aliases S) ---
    short* ff = (short*)S;
    gemm8<1, 1, 0, 1><<<dim3(16, 32, 1), 512, SHBYTES, stream>>>(
        h, 1024, 0, WinT, 1024, 0, ff, 4096, 0, bin, nullptr, 0, 0, 1024);

    // --- FF2: out = ff @ Wout + bout + x1 : M=8192 N=1024 K=4096, fp32 out ---
    gemm8<1, 0, 1, 0><<<dim3(4, 32, 1), 512, SHBYTES, stream>>>(
        ff, 4096, 0, WoutT, 4096, 0, (float*)d_out, 1024, 0, bout,
        x1, 1024, 0, 4096);
}